// Round 15
// baseline (161.961 us; speedup 1.0000x reference)
//
#include <hip/hip_runtime.h>
#include <math.h>

#define NSAMP 262144
#define NW 4
#define BLK 256
#define PB 1024           // phys blocks: 16384 iters / 4096 waves = exactly 4
#define DB 256            // data blocks:  4096 iters / 1024 waves = exactly 4
#define GRID (PB + DB)    // 1280 = 5 blocks/CU, perfectly load-balanced

// sched_barrier mask: DS-reads (0x100) + VMEM-reads (0x20) may cross; VALU /
// MFMA / DS-writes stay pinned (the pin is what keeps live pressure at the
// source-level ~80 regs -- r11). Allowing read hoisting hides per-rt LDS
// latency and per-iter global-load latency that 0x0 exposed.
#define SB_MASK 0x120

typedef _Float16 f16x8 __attribute__((ext_vector_type(8)));
typedef _Float16 f16x4 __attribute__((ext_vector_type(4)));
typedef __fp16   fp16x2 __attribute__((ext_vector_type(2)));
typedef float    f32x4 __attribute__((ext_vector_type(4)));

// 4 channels. PHYS = {0:val, 1:d/dx, 2:d/dy, 3:combo z* = z_t - alpha*(z_xx+z_yy)}
// combo closed under propagation: h* = ap*z* - alpha*app*(z1^2+z2^2); residual = W4^T h*.
// DATA = 4 independent samples. (verified absmax 0.0, r9-r14)
#define NCH 4

__device__ __forceinline__ float fast_tanh(float x) {
    float e = __expf(2.0f * x);
    float r = __builtin_amdgcn_rcpf(e + 1.0f);
    return 1.0f - 2.0f * r;
}

__device__ __forceinline__ f16x4 pk4(float a, float b, float c, float d) {
    union { f16x4 v; fp16x2 h[2]; } u;
    u.h[0] = __builtin_amdgcn_cvt_pkrtz(a, b);
    u.h[1] = __builtin_amdgcn_cvt_pkrtz(c, d);
    return u.v;
}

__device__ __forceinline__ void set_half(f16x8& dst, f16x4 v, int hi) {
    if (hi == 0) { dst[0] = v[0]; dst[1] = v[1]; dst[2] = v[2]; dst[3] = v[3]; }
    else         { dst[4] = v[0]; dst[5] = v[1]; dst[6] = v[2]; dst[7] = v[3]; }
}

__device__ __forceinline__ double shfl_xor_d(double v, int m) {
    union { double d; int i[2]; } u; u.d = v;
    u.i[0] = __shfl_xor(u.i[0], m, 64);
    u.i[1] = __shfl_xor(u.i[1], m, 64);
    return u.d;
}

template<bool DATA>
__device__ __forceinline__ void pw(const f32x4* acc, f16x4* out, float alpha)
{
    float h[NCH][4];
    #pragma unroll
    for (int r = 0; r < 4; r++) {
        if (DATA) {
            #pragma unroll
            for (int c = 0; c < NCH; c++) h[c][r] = fast_tanh(acc[c][r]);
        } else {
            float z1 = acc[1][r], z2 = acc[2][r];
            float a    = fast_tanh(acc[0][r]);
            float ap   = 1.0f - a * a;
            float napp = 2.0f * a * ap * alpha;    // = -alpha*app
            h[0][r] = a;
            h[1][r] = ap * z1;
            h[2][r] = ap * z2;
            h[3][r] = ap * acc[3][r] + napp * (z1 * z1 + z2 * z2);
        }
    }
    #pragma unroll
    for (int c = 0; c < NCH; c++)
        out[c] = pk4(h[c][0], h[c][1], h[c][2], h[c][3]);
}

template<bool DATA>
__device__ __forceinline__ void layer_mfma(
    const _Float16* sWA, const float (*sB)[64],
    int l, int rt, int q, int n, const f16x8 (&bf)[NCH][2], f32x4 (&acc)[NCH])
{
    const f32x4 z4 = {0.f, 0.f, 0.f, 0.f};
    f16x8 a0k = *(const f16x8*)&sWA[((((l * 4 + rt) * 2 + 0) * 4 + q) * 16 + n) * 8];
    f16x8 a1k = *(const f16x8*)&sWA[((((l * 4 + rt) * 2 + 1) * 4 + q) * 16 + n) * 8];
    f32x4 bias = *(const f32x4*)&sB[l + 1][rt * 16 + q * 4];
    #pragma unroll
    for (int c = 0; c < NCH; c++) {
        f32x4 cin = (DATA || c == 0) ? bias : z4;
        acc[c] = __builtin_amdgcn_mfma_f32_16x16x32_f16(a0k, bf[c][0], cin, 0, 0, 0);
        acc[c] = __builtin_amdgcn_mfma_f32_16x16x32_f16(a1k, bf[c][1], acc[c], 0, 0, 0);
    }
}

template<bool DATA>
__device__ __forceinline__ void hidden_layer(
    const _Float16* sWA, const float (*sB)[64],
    int l, int q, int n, const f16x8 (&bin)[NCH][2], f16x8 (&bout)[NCH][2], float alpha)
{
    #pragma unroll
    for (int rt = 0; rt < 4; rt++) {
        f32x4 acc[NCH];
        layer_mfma<DATA>(sWA, sB, l, rt, q, n, bin, acc);
        f16x4 t6[NCH];
        pw<DATA>(acc, t6, alpha);
        #pragma unroll
        for (int c = 0; c < NCH; c++) set_half(bout[c][rt >> 1], t6[c], rt & 1);
        // Pin VALU/MFMA order at rt granularity (stops the pressure-inflating
        // hoists of r7-r10) but let memory READS cross for latency hiding.
        __builtin_amdgcn_sched_barrier(SB_MASK);
    }
}

template<bool DATA>
__device__ __forceinline__ double run_mode(
    const float* __restrict__ xd, const float* __restrict__ yd,
    const float* __restrict__ xp, float alpha,
    const _Float16* sWA, const f16x8 (&a0r)[4],
    const float (*sB)[64], const float* sW4, float b4,
    int q, int n, int wstart, int wstride)
{
    const f16x8 zf = {0, 0, 0, 0, 0, 0, 0, 0};
    const f32x4 z4 = {0.f, 0.f, 0.f, 0.f};

    const int NIT = DATA ? (NSAMP / (16 * NCH)) : (NSAMP / 16);
    double dacc = 0.0;

    for (int it = wstart; it < NIT; it += wstride) {
        f16x8 bfA[NCH][2], bfB[NCH][2];     // ping-pong, always constant-indexed
        // ---------------- layer 0 (K=32 padded, k<3 nonzero; A-frags in regs) ----------------
        {
            f16x8 b0f[NCH];
            #pragma unroll
            for (int c = 0; c < NCH; c++) b0f[c] = zf;
            if (DATA) {
                if (q == 0) {
                    #pragma unroll
                    for (int c = 0; c < NCH; c++) {
                        int s = it * (16 * NCH) + c * 16 + n;
                        b0f[c][0] = (_Float16)xd[s * 3 + 0];
                        b0f[c][1] = (_Float16)xd[s * 3 + 1];
                        b0f[c][2] = (_Float16)xd[s * 3 + 2];
                    }
                }
            } else {
                if (q == 0) {
                    int s = it * 16 + n;
                    b0f[0][0] = (_Float16)xp[s * 3 + 0];
                    b0f[0][1] = (_Float16)xp[s * 3 + 1];
                    b0f[0][2] = (_Float16)xp[s * 3 + 2];
                    b0f[1][0] = (_Float16)1.0f;   // d/dx seed
                    b0f[2][1] = (_Float16)1.0f;   // d/dy seed
                    b0f[3][2] = (_Float16)1.0f;   // combo seed: z*0 = z_t
                }
            }
            #pragma unroll
            for (int rt = 0; rt < 4; rt++) {
                f32x4 bias = *(const f32x4*)&sB[0][rt * 16 + q * 4];
                f32x4 acc[NCH];
                if (DATA) {
                    #pragma unroll
                    for (int c = 0; c < NCH; c++)
                        acc[c] = __builtin_amdgcn_mfma_f32_16x16x32_f16(a0r[rt], b0f[c], bias, 0, 0, 0);
                } else {
                    acc[0] = __builtin_amdgcn_mfma_f32_16x16x32_f16(a0r[rt], b0f[0], bias, 0, 0, 0);
                    #pragma unroll
                    for (int c = 1; c < NCH; c++)
                        acc[c] = __builtin_amdgcn_mfma_f32_16x16x32_f16(a0r[rt], b0f[c], z4, 0, 0, 0);
                }
                f16x4 t6[NCH];
                pw<DATA>(acc, t6, alpha);
                #pragma unroll
                for (int c = 0; c < NCH; c++) set_half(bfA[c][rt >> 1], t6[c], rt & 1);
                __builtin_amdgcn_sched_barrier(SB_MASK);
            }
        }

        // ---------------- hidden layers, manually unrolled ping-pong ----------------
        hidden_layer<DATA>(sWA, sB, 0, q, n, bfA, bfB, alpha);
        hidden_layer<DATA>(sWA, sB, 1, q, n, bfB, bfA, alpha);

        // ---------------- last hidden layer + fold 64->1 into partials ----------------
        float t[NCH] = {0.f, 0.f, 0.f, 0.f};      // DATA partials
        float tr = 0.f;                            // PHYS residual partial
        #pragma unroll
        for (int rt = 0; rt < 4; rt++) {
            f32x4 acc[NCH];
            layer_mfma<DATA>(sWA, sB, 2, rt, q, n, bfA, acc);
            f32x4 w4v = *(const f32x4*)&sW4[rt * 16 + q * 4];
            #pragma unroll
            for (int r = 0; r < 4; r++) {
                float w = w4v[r];
                if (DATA) {
                    #pragma unroll
                    for (int c = 0; c < NCH; c++) t[c] += w * fast_tanh(acc[c][r]);
                } else {
                    float z1 = acc[1][r], z2 = acc[2][r];
                    float a    = fast_tanh(acc[0][r]);
                    float ap   = 1.0f - a * a;
                    float napp = 2.0f * a * ap * alpha;
                    tr += w * (ap * acc[3][r] + napp * (z1 * z1 + z2 * z2));
                }
            }
            // no barrier: no bout stores -> low pressure; free overlap.
        }

        // ---------------- epilogue ----------------
        if (DATA) {
            #pragma unroll
            for (int c = 0; c < NCH; c++) {
                t[c] += __shfl_xor(t[c], 16, 64);
                t[c] += __shfl_xor(t[c], 32, 64);
            }
            if (q == 0) {
                #pragma unroll
                for (int c = 0; c < NCH; c++) {
                    int s = it * (16 * NCH) + c * 16 + n;
                    float d = t[c] + b4 - yd[s];
                    dacc += (double)d * (double)d;
                }
            }
        } else {
            tr += __shfl_xor(tr, 16, 64);
            tr += __shfl_xor(tr, 32, 64);
            if (q == 0) dacc += (double)tr * (double)tr;
        }
    }
    return dacc;
}

// waves_per_eu(2,5): 5-waves/EU target (budget 512/5=102 >= live set)
// -> 20 waves/CU, zero spills (r12/r14). Grid 1280: exactly 4 iters/wave
// both modes; 6 blocks/CU cannot be balanced for 20480 iters (r13).
__global__ __launch_bounds__(BLK)
__attribute__((amdgpu_waves_per_eu(2, 5)))
void fused_kernel(
    const float* __restrict__ xd, const float* __restrict__ yd, const float* __restrict__ xp,
    const float* __restrict__ W0, const float* __restrict__ b0,
    const float* __restrict__ W1, const float* __restrict__ b1,
    const float* __restrict__ W2, const float* __restrict__ b2,
    const float* __restrict__ W3, const float* __restrict__ b3,
    const float* __restrict__ W4, const float* __restrict__ b4,
    const float* __restrict__ log_alpha,
    double* __restrict__ accg)     // accg[blockIdx.x] = block partial
{
    __shared__ __align__(16) _Float16 sWA[3 * 4 * 2 * 4 * 16 * 8];   // 24576 B
    __shared__ __align__(16) float sB[4][64];
    __shared__ __align__(16) float sW4s[64];
    __shared__ float sb4;
    __shared__ double sRed[NW];

    const int tid = threadIdx.x;
    // Hidden-layer A-frags with neuron relabel p(k):
    //   A_l[m][k] = W_l[p(k)][m],  p(k) = rt*16 + q*4 + r,
    //   rt = 2*(k>>5) + ((k>>2)&1), q = (k>>3)&3, r = k&3.
    // Makes the C->B layer transition lane-local (verified absmax 0.0, r5-r14).
    for (int idx = tid; idx < 3 * 4096; idx += BLK) {
        int l = idx >> 12, rem = idx & 4095, k = rem >> 6, m = rem & 63;
        const float* Ws = (l == 0) ? W1 : (l == 1) ? W2 : W3;   // [in][out]
        int pk_ = (2 * (k >> 5) + ((k >> 2) & 1)) * 16 + ((k >> 3) & 3) * 4 + (k & 3);
        int rt = m >> 4, mlo = m & 15, kt = k >> 5, qq = (k >> 3) & 3, j = k & 7;
        sWA[((((l * 4 + rt) * 2 + kt) * 4 + qq) * 16 + mlo) * 8 + j] = (_Float16)Ws[pk_ * 64 + m];
    }
    for (int i = tid; i < 64; i += BLK) {
        sB[0][i] = b0[i]; sB[1][i] = b1[i]; sB[2][i] = b2[i]; sB[3][i] = b3[i];
        sW4s[i] = W4[i];
    }
    if (tid == 0) sb4 = b4[0];

    const int wave = tid >> 6, lane = tid & 63;
    const int q = lane >> 4, n = lane & 15;
    const float alpha = __expf(log_alpha[0]);

    // layer-0 A-frags in registers (loop-invariant; only q==0 lanes non-zero).
    f16x8 a0r[4];
    #pragma unroll
    for (int rt = 0; rt < 4; rt++) {
        f16x8 v = {0, 0, 0, 0, 0, 0, 0, 0};
        if (q == 0) {
            v[0] = (_Float16)W0[0 * 64 + rt * 16 + n];
            v[1] = (_Float16)W0[1 * 64 + rt * 16 + n];
            v[2] = (_Float16)W0[2 * 64 + rt * 16 + n];
        }
        a0r[rt] = v;
    }
    __syncthreads();

    double dacc;
    if (blockIdx.x < PB) {
        int ws = blockIdx.x * NW + wave;
        dacc = run_mode<false>(xd, yd, xp, alpha, sWA, a0r, sB, sW4s, sb4,
                               q, n, ws, PB * NW);
    } else {
        int ws = (blockIdx.x - PB) * NW + wave;
        dacc = run_mode<true>(xd, yd, xp, alpha, sWA, a0r, sB, sW4s, sb4,
                              q, n, ws, DB * NW);
    }
    #pragma unroll
    for (int m = 1; m < 64; m <<= 1) dacc = dacc + shfl_xor_d(dacc, m);
    if (lane == 0) sRed[wave] = dacc;
    __syncthreads();
    if (tid == 0)
        accg[blockIdx.x] = sRed[0] + sRed[1] + sRed[2] + sRed[3];
}

__global__ void finalize_kernel(const double* __restrict__ ws,
                                const float* __restrict__ log_lambda,
                                const float* __restrict__ log_alpha,
                                float* __restrict__ out)
{
    __shared__ double sp[256], sd[256];
    int tid = threadIdx.x;
    double pd = 0.0, dd = 0.0;
    for (int i = tid; i < PB; i += 256) pd += ws[i];
    for (int i = PB + tid; i < GRID; i += 256) dd += ws[i];
    sp[tid] = pd; sd[tid] = dd;
    __syncthreads();
    for (int s = 128; s > 0; s >>= 1) {
        if (tid < s) { sp[tid] += sp[tid + s]; sd[tid] += sd[tid + s]; }
        __syncthreads();
    }
    if (tid == 0) {
        float pde_loss  = (float)(sp[0] / (double)NSAMP);
        float data_loss = (float)(sd[0] / (double)NSAMP);
        float alpha = expf(log_alpha[0]);
        float lam   = expf(log_lambda[0]);
        out[0] = data_loss + lam * pde_loss;
        out[1] = data_loss;
        out[2] = pde_loss;
        out[3] = alpha;
        out[4] = lam;
    }
}

extern "C" void kernel_launch(void* const* d_in, const int* in_sizes, int n_in,
                              void* d_out, int out_size, void* d_ws, size_t ws_size,
                              hipStream_t stream) {
    const float* xd = (const float*)d_in[0];
    const float* yd = (const float*)d_in[1];
    const float* xp = (const float*)d_in[2];
    const float* W0 = (const float*)d_in[3];
    const float* b0 = (const float*)d_in[4];
    const float* W1 = (const float*)d_in[5];
    const float* b1 = (const float*)d_in[6];
    const float* W2 = (const float*)d_in[7];
    const float* b2 = (const float*)d_in[8];
    const float* W3 = (const float*)d_in[9];
    const float* b3 = (const float*)d_in[10];
    const float* W4 = (const float*)d_in[11];
    const float* b4 = (const float*)d_in[12];
    const float* log_lambda = (const float*)d_in[13];
    const float* log_alpha  = (const float*)d_in[14];
    float* out = (float*)d_out;
    double* acc = (double*)d_ws;   // GRID doubles of per-block partials

    fused_kernel<<<GRID, BLK, 0, stream>>>(xd, yd, xp, W0, b0, W1, b1, W2, b2, W3, b3,
                                           W4, b4, log_alpha, acc);
    finalize_kernel<<<1, 256, 0, stream>>>(acc, log_lambda, log_alpha, out);
}

// Round 16
// 151.455 us; speedup vs baseline: 1.0694x; 1.0694x over previous
//
#include <hip/hip_runtime.h>
#include <math.h>

#define NSAMP 262144
#define NW 4
#define BLK 256
#define PB 1024           // phys blocks: 16384 iters / 4096 waves = exactly 4
#define DB 256            // data blocks:  4096 iters / 1024 waves = exactly 4
#define GRID (PB + DB)    // 1280 = 5 blocks/CU, perfectly load-balanced

// sched_barrier mask: DS/VMEM reads may cross; VALU/MFMA/DS-writes pinned.
#define SB_MASK 0x120

typedef _Float16 f16x8 __attribute__((ext_vector_type(8)));
typedef _Float16 f16x4 __attribute__((ext_vector_type(4)));
typedef __fp16   fp16x2 __attribute__((ext_vector_type(2)));
typedef float    f32x4 __attribute__((ext_vector_type(4)));
typedef float    f32x2 __attribute__((ext_vector_type(2)));

// 4 channels. PHYS = {0:val, 1:d/dx, 2:d/dy, 3:combo z* = z_t - alpha*(z_xx+z_yy)}
// combo closed under propagation: h* = ap*z* - alpha*app*(z1^2+z2^2); residual = W4^T h*.
// DATA = 4 independent samples. (verified absmax 0.0, r9-r15)
#define NCH 4

#define TWO_LOG2E 2.8853900817779268f   // 2*log2(e): expf(2x) = exp2(x*TWO_LOG2E)

__device__ __forceinline__ f32x2 lo2(f32x4 v) { return __builtin_shufflevector(v, v, 0, 1); }
__device__ __forceinline__ f32x2 hi2(f32x4 v) { return __builtin_shufflevector(v, v, 2, 3); }
__device__ __forceinline__ f32x2 splat2(float s) { f32x2 v; v.x = s; v.y = s; return v; }

// pair tanh: elementwise-identical math to the scalar fast_tanh; the mul/add/
// fma stages are <2 x float> so the backend can select v_pk_*_f32 (VOP3P).
__device__ __forceinline__ f32x2 fast_tanh2(f32x2 x) {
    f32x2 t = x * splat2(TWO_LOG2E);
    f32x2 e;
    e.x = __builtin_amdgcn_exp2f(t.x);
    e.y = __builtin_amdgcn_exp2f(t.y);
    f32x2 d = e + splat2(1.0f);
    f32x2 rc;
    rc.x = __builtin_amdgcn_rcpf(d.x);
    rc.y = __builtin_amdgcn_rcpf(d.y);
    return splat2(1.0f) - splat2(2.0f) * rc;
}

// PHYS pointwise on an r-pair: z* channels in, h* channels out (packed math).
__device__ __forceinline__ void phys_half(f32x2 z0, f32x2 z1, f32x2 z2, f32x2 z3,
                                          f32x2 alpha2, f32x2 (&h)[NCH])
{
    f32x2 a    = fast_tanh2(z0);
    f32x2 ap   = splat2(1.0f) - a * a;
    f32x2 napp = (a * ap) * alpha2;          // = -alpha*app = 2*alpha*a*ap
    h[0] = a;
    h[1] = ap * z1;
    h[2] = ap * z2;
    f32x2 s = z1 * z1 + z2 * z2;
    h[3] = ap * z3 + napp * s;
}

__device__ __forceinline__ f16x4 pkpair(f32x2 lo, f32x2 hi) {
    union { f16x4 v; fp16x2 h[2]; } u;
    u.h[0] = __builtin_amdgcn_cvt_pkrtz(lo.x, lo.y);
    u.h[1] = __builtin_amdgcn_cvt_pkrtz(hi.x, hi.y);
    return u.v;
}

__device__ __forceinline__ void set_half(f16x8& dst, f16x4 v, int hi) {
    if (hi == 0) { dst[0] = v[0]; dst[1] = v[1]; dst[2] = v[2]; dst[3] = v[3]; }
    else         { dst[4] = v[0]; dst[5] = v[1]; dst[6] = v[2]; dst[7] = v[3]; }
}

__device__ __forceinline__ double shfl_xor_d(double v, int m) {
    union { double d; int i[2]; } u; u.d = v;
    u.i[0] = __shfl_xor(u.i[0], m, 64);
    u.i[1] = __shfl_xor(u.i[1], m, 64);
    return u.d;
}

// pointwise on one rt's acc[NCH] -> packed f16x4/channel, via f32x2 pairs.
template<bool DATA>
__device__ __forceinline__ void pw(const f32x4* acc, f16x4* out, f32x2 alpha2)
{
    if (DATA) {
        #pragma unroll
        for (int c = 0; c < NCH; c++)
            out[c] = pkpair(fast_tanh2(lo2(acc[c])), fast_tanh2(hi2(acc[c])));
    } else {
        f32x2 hlo[NCH], hhi[NCH];
        phys_half(lo2(acc[0]), lo2(acc[1]), lo2(acc[2]), lo2(acc[3]), alpha2, hlo);
        phys_half(hi2(acc[0]), hi2(acc[1]), hi2(acc[2]), hi2(acc[3]), alpha2, hhi);
        #pragma unroll
        for (int c = 0; c < NCH; c++) out[c] = pkpair(hlo[c], hhi[c]);
    }
}

template<bool DATA>
__device__ __forceinline__ void layer_mfma(
    const _Float16* sWA, const float (*sB)[64],
    int l, int rt, int q, int n, const f16x8 (&bf)[NCH][2], f32x4 (&acc)[NCH])
{
    const f32x4 z4 = {0.f, 0.f, 0.f, 0.f};
    f16x8 a0k = *(const f16x8*)&sWA[((((l * 4 + rt) * 2 + 0) * 4 + q) * 16 + n) * 8];
    f16x8 a1k = *(const f16x8*)&sWA[((((l * 4 + rt) * 2 + 1) * 4 + q) * 16 + n) * 8];
    f32x4 bias = *(const f32x4*)&sB[l + 1][rt * 16 + q * 4];
    #pragma unroll
    for (int c = 0; c < NCH; c++) {
        f32x4 cin = (DATA || c == 0) ? bias : z4;
        acc[c] = __builtin_amdgcn_mfma_f32_16x16x32_f16(a0k, bf[c][0], cin, 0, 0, 0);
        acc[c] = __builtin_amdgcn_mfma_f32_16x16x32_f16(a1k, bf[c][1], acc[c], 0, 0, 0);
    }
}

template<bool DATA>
__device__ __forceinline__ void hidden_layer(
    const _Float16* sWA, const float (*sB)[64],
    int l, int q, int n, const f16x8 (&bin)[NCH][2], f16x8 (&bout)[NCH][2], f32x2 alpha2)
{
    #pragma unroll
    for (int rt = 0; rt < 4; rt++) {
        f32x4 acc[NCH];
        layer_mfma<DATA>(sWA, sB, l, rt, q, n, bin, acc);
        f16x4 t6[NCH];
        pw<DATA>(acc, t6, alpha2);
        #pragma unroll
        for (int c = 0; c < NCH; c++) set_half(bout[c][rt >> 1], t6[c], rt & 1);
        // Pin VALU/MFMA order at rt granularity (kills the r7-r10 spill hoists).
        __builtin_amdgcn_sched_barrier(SB_MASK);
    }
}

template<bool DATA>
__device__ __forceinline__ double run_mode(
    const float* __restrict__ xd, const float* __restrict__ yd,
    const float* __restrict__ xp, float alpha,
    const _Float16* sWA, const f16x8 (&a0r)[4],
    const float (*sB)[64], const float* sW4, float b4,
    int q, int n, int wstart, int wstride)
{
    const f16x8 zf = {0, 0, 0, 0, 0, 0, 0, 0};
    const f32x4 z4 = {0.f, 0.f, 0.f, 0.f};
    const f32x2 alpha2 = splat2(2.0f * alpha);

    const int NIT = DATA ? (NSAMP / (16 * NCH)) : (NSAMP / 16);
    double dacc = 0.0;

    for (int it = wstart; it < NIT; it += wstride) {
        f16x8 bfA[NCH][2], bfB[NCH][2];     // ping-pong, always constant-indexed
        // ---------------- layer 0 (K=32 padded, k<3 nonzero; A-frags in regs) ----------------
        {
            f16x8 b0f[NCH];
            #pragma unroll
            for (int c = 0; c < NCH; c++) b0f[c] = zf;
            if (DATA) {
                if (q == 0) {
                    #pragma unroll
                    for (int c = 0; c < NCH; c++) {
                        int s = it * (16 * NCH) + c * 16 + n;
                        b0f[c][0] = (_Float16)xd[s * 3 + 0];
                        b0f[c][1] = (_Float16)xd[s * 3 + 1];
                        b0f[c][2] = (_Float16)xd[s * 3 + 2];
                    }
                }
            } else {
                if (q == 0) {
                    int s = it * 16 + n;
                    b0f[0][0] = (_Float16)xp[s * 3 + 0];
                    b0f[0][1] = (_Float16)xp[s * 3 + 1];
                    b0f[0][2] = (_Float16)xp[s * 3 + 2];
                    b0f[1][0] = (_Float16)1.0f;   // d/dx seed
                    b0f[2][1] = (_Float16)1.0f;   // d/dy seed
                    b0f[3][2] = (_Float16)1.0f;   // combo seed: z*0 = z_t
                }
            }
            #pragma unroll
            for (int rt = 0; rt < 4; rt++) {
                f32x4 bias = *(const f32x4*)&sB[0][rt * 16 + q * 4];
                f32x4 acc[NCH];
                if (DATA) {
                    #pragma unroll
                    for (int c = 0; c < NCH; c++)
                        acc[c] = __builtin_amdgcn_mfma_f32_16x16x32_f16(a0r[rt], b0f[c], bias, 0, 0, 0);
                } else {
                    acc[0] = __builtin_amdgcn_mfma_f32_16x16x32_f16(a0r[rt], b0f[0], bias, 0, 0, 0);
                    #pragma unroll
                    for (int c = 1; c < NCH; c++)
                        acc[c] = __builtin_amdgcn_mfma_f32_16x16x32_f16(a0r[rt], b0f[c], z4, 0, 0, 0);
                }
                f16x4 t6[NCH];
                pw<DATA>(acc, t6, alpha2);
                #pragma unroll
                for (int c = 0; c < NCH; c++) set_half(bfA[c][rt >> 1], t6[c], rt & 1);
                __builtin_amdgcn_sched_barrier(SB_MASK);
            }
        }

        // ---------------- hidden layers, manually unrolled ping-pong ----------------
        hidden_layer<DATA>(sWA, sB, 0, q, n, bfA, bfB, alpha2);
        hidden_layer<DATA>(sWA, sB, 1, q, n, bfB, bfA, alpha2);

        // ---------------- last hidden layer + fold 64->1 into partials (paired) ----------------
        f32x2 t2[NCH];                             // DATA partials (pair accumulators)
        #pragma unroll
        for (int c = 0; c < NCH; c++) t2[c] = splat2(0.f);
        f32x2 tr2 = splat2(0.f);                   // PHYS residual pair accumulator
        #pragma unroll
        for (int rt = 0; rt < 4; rt++) {
            f32x4 acc[NCH];
            layer_mfma<DATA>(sWA, sB, 2, rt, q, n, bfA, acc);
            f32x4 w4v = *(const f32x4*)&sW4[rt * 16 + q * 4];
            f32x2 wlo = lo2(w4v), whi = hi2(w4v);
            if (DATA) {
                #pragma unroll
                for (int c = 0; c < NCH; c++) {
                    t2[c] = t2[c] + wlo * fast_tanh2(lo2(acc[c]));
                    t2[c] = t2[c] + whi * fast_tanh2(hi2(acc[c]));
                }
            } else {
                f32x2 hlo[NCH], hhi[NCH];
                phys_half(lo2(acc[0]), lo2(acc[1]), lo2(acc[2]), lo2(acc[3]), alpha2, hlo);
                phys_half(hi2(acc[0]), hi2(acc[1]), hi2(acc[2]), hi2(acc[3]), alpha2, hhi);
                tr2 = tr2 + wlo * hlo[3];
                tr2 = tr2 + whi * hhi[3];
            }
        }

        // ---------------- epilogue ----------------
        if (DATA) {
            float t[NCH];
            #pragma unroll
            for (int c = 0; c < NCH; c++) {
                t[c] = t2[c].x + t2[c].y;
                t[c] += __shfl_xor(t[c], 16, 64);
                t[c] += __shfl_xor(t[c], 32, 64);
            }
            if (q == 0) {
                #pragma unroll
                for (int c = 0; c < NCH; c++) {
                    int s = it * (16 * NCH) + c * 16 + n;
                    float d = t[c] + b4 - yd[s];
                    dacc += (double)d * (double)d;
                }
            }
        } else {
            float tr = tr2.x + tr2.y;
            tr += __shfl_xor(tr, 16, 64);
            tr += __shfl_xor(tr, 32, 64);
            if (q == 0) dacc += (double)tr * (double)tr;
        }
    }
    return dacc;
}

// waves_per_eu(2,5): 5-waves/EU target (budget 102 >= live set) -> 20 waves/CU,
// zero spills (r12/r14/r15). Grid 1280: exactly 4 iters/wave in both modes.
__global__ __launch_bounds__(BLK)
__attribute__((amdgpu_waves_per_eu(2, 5)))
void fused_kernel(
    const float* __restrict__ xd, const float* __restrict__ yd, const float* __restrict__ xp,
    const float* __restrict__ W0, const float* __restrict__ b0,
    const float* __restrict__ W1, const float* __restrict__ b1,
    const float* __restrict__ W2, const float* __restrict__ b2,
    const float* __restrict__ W3, const float* __restrict__ b3,
    const float* __restrict__ W4, const float* __restrict__ b4,
    const float* __restrict__ log_alpha,
    double* __restrict__ accg)     // accg[blockIdx.x] = block partial
{
    __shared__ __align__(16) _Float16 sWA[3 * 4 * 2 * 4 * 16 * 8];   // 24576 B
    __shared__ __align__(16) float sB[4][64];
    __shared__ __align__(16) float sW4s[64];
    __shared__ float sb4;
    __shared__ double sRed[NW];

    const int tid = threadIdx.x;
    // Hidden-layer A-frags with neuron relabel p(k):
    //   A_l[m][k] = W_l[p(k)][m],  p(k) = rt*16 + q*4 + r,
    //   rt = 2*(k>>5) + ((k>>2)&1), q = (k>>3)&3, r = k&3.
    // Makes the C->B layer transition lane-local (verified absmax 0.0, r5-r15).
    for (int idx = tid; idx < 3 * 4096; idx += BLK) {
        int l = idx >> 12, rem = idx & 4095, k = rem >> 6, m = rem & 63;
        const float* Ws = (l == 0) ? W1 : (l == 1) ? W2 : W3;   // [in][out]
        int pk_ = (2 * (k >> 5) + ((k >> 2) & 1)) * 16 + ((k >> 3) & 3) * 4 + (k & 3);
        int rt = m >> 4, mlo = m & 15, kt = k >> 5, qq = (k >> 3) & 3, j = k & 7;
        sWA[((((l * 4 + rt) * 2 + kt) * 4 + qq) * 16 + mlo) * 8 + j] = (_Float16)Ws[pk_ * 64 + m];
    }
    for (int i = tid; i < 64; i += BLK) {
        sB[0][i] = b0[i]; sB[1][i] = b1[i]; sB[2][i] = b2[i]; sB[3][i] = b3[i];
        sW4s[i] = W4[i];
    }
    if (tid == 0) sb4 = b4[0];

    const int wave = tid >> 6, lane = tid & 63;
    const int q = lane >> 4, n = lane & 15;
    const float alpha = __expf(log_alpha[0]);

    // layer-0 A-frags in registers (loop-invariant; only q==0 lanes non-zero).
    f16x8 a0r[4];
    #pragma unroll
    for (int rt = 0; rt < 4; rt++) {
        f16x8 v = {0, 0, 0, 0, 0, 0, 0, 0};
        if (q == 0) {
            v[0] = (_Float16)W0[0 * 64 + rt * 16 + n];
            v[1] = (_Float16)W0[1 * 64 + rt * 16 + n];
            v[2] = (_Float16)W0[2 * 64 + rt * 16 + n];
        }
        a0r[rt] = v;
    }
    __syncthreads();

    double dacc;
    if (blockIdx.x < PB) {
        int ws = blockIdx.x * NW + wave;
        dacc = run_mode<false>(xd, yd, xp, alpha, sWA, a0r, sB, sW4s, sb4,
                               q, n, ws, PB * NW);
    } else {
        int ws = (blockIdx.x - PB) * NW + wave;
        dacc = run_mode<true>(xd, yd, xp, alpha, sWA, a0r, sB, sW4s, sb4,
                              q, n, ws, DB * NW);
    }
    #pragma unroll
    for (int m = 1; m < 64; m <<= 1) dacc = dacc + shfl_xor_d(dacc, m);
    if (lane == 0) sRed[wave] = dacc;
    __syncthreads();
    if (tid == 0)
        accg[blockIdx.x] = sRed[0] + sRed[1] + sRed[2] + sRed[3];
}

__global__ void finalize_kernel(const double* __restrict__ ws,
                                const float* __restrict__ log_lambda,
                                const float* __restrict__ log_alpha,
                                float* __restrict__ out)
{
    __shared__ double sp[256], sd[256];
    int tid = threadIdx.x;
    double pd = 0.0, dd = 0.0;
    for (int i = tid; i < PB; i += 256) pd += ws[i];
    for (int i = PB + tid; i < GRID; i += 256) dd += ws[i];
    sp[tid] = pd; sd[tid] = dd;
    __syncthreads();
    for (int s = 128; s > 0; s >>= 1) {
        if (tid < s) { sp[tid] += sp[tid + s]; sd[tid] += sd[tid + s]; }
        __syncthreads();
    }
    if (tid == 0) {
        float pde_loss  = (float)(sp[0] / (double)NSAMP);
        float data_loss = (float)(sd[0] / (double)NSAMP);
        float alpha = expf(log_alpha[0]);
        float lam   = expf(log_lambda[0]);
        out[0] = data_loss + lam * pde_loss;
        out[1] = data_loss;
        out[2] = pde_loss;
        out[3] = alpha;
        out[4] = lam;
    }
}

extern "C" void kernel_launch(void* const* d_in, const int* in_sizes, int n_in,
                              void* d_out, int out_size, void* d_ws, size_t ws_size,
                              hipStream_t stream) {
    const float* xd = (const float*)d_in[0];
    const float* yd = (const float*)d_in[1];
    const float* xp = (const float*)d_in[2];
    const float* W0 = (const float*)d_in[3];
    const float* b0 = (const float*)d_in[4];
    const float* W1 = (const float*)d_in[5];
    const float* b1 = (const float*)d_in[6];
    const float* W2 = (const float*)d_in[7];
    const float* b2 = (const float*)d_in[8];
    const float* W3 = (const float*)d_in[9];
    const float* b3 = (const float*)d_in[10];
    const float* W4 = (const float*)d_in[11];
    const float* b4 = (const float*)d_in[12];
    const float* log_lambda = (const float*)d_in[13];
    const float* log_alpha  = (const float*)d_in[14];
    float* out = (float*)d_out;
    double* acc = (double*)d_ws;   // GRID doubles of per-block partials

    fused_kernel<<<GRID, BLK, 0, stream>>>(xd, yd, xp, W0, b0, W1, b1, W2, b2, W3, b3,
                                           W4, b4, log_alpha, acc);
    finalize_kernel<<<1, 256, 0, stream>>>(acc, log_lambda, log_alpha, out);
}